// Round 5
// baseline (215.010 us; speedup 1.0000x reference)
//
#include <hip/hip_runtime.h>

#define EPSB 1e-5f

typedef __bf16 bf16x8 __attribute__((ext_vector_type(8)));
typedef float f32x4 __attribute__((ext_vector_type(4)));
typedef float f32x16 __attribute__((ext_vector_type(16)));

__device__ __forceinline__ unsigned short bfc(float v) {
  __bf16 h = (__bf16)v;
  return __builtin_bit_cast(unsigned short, h);
}
__device__ __forceinline__ unsigned int pk2(float a, float b) {
  return (unsigned int)bfc(a) | ((unsigned int)bfc(b) << 16);
}
__device__ __forceinline__ float lo16f(unsigned int u) {
  union { unsigned int u; float f; } v; v.u = u << 16; return v.f;
}
__device__ __forceinline__ float hi16f(unsigned int u) {
  union { unsigned int u; float f; } v; v.u = u & 0xFFFF0000u; return v.f;
}
__device__ __forceinline__ float sigm(float x) {
  float e = __builtin_amdgcn_exp2f(-x * 1.4426950408889634f);
  return __builtin_amdgcn_rcpf(1.0f + e);
}

// ---------------- prep: fold BN into bf16 weights ----------------
__global__ void prep_kernel(
    const float* __restrict__ w_att, const float* __restrict__ b_att,
    const float* __restrict__ gA, const float* __restrict__ beA,
    const float* __restrict__ mA, const float* __restrict__ vA,
    const float* __restrict__ w1, const float* __restrict__ b1,
    const float* __restrict__ g1, const float* __restrict__ be1,
    const float* __restrict__ m1, const float* __restrict__ v1,
    const float* __restrict__ w2, const float* __restrict__ b2,
    const float* __restrict__ g2, const float* __restrict__ be2,
    const float* __restrict__ m2, const float* __restrict__ v2,
    unsigned short* __restrict__ wAe, unsigned short* __restrict__ w1e,
    unsigned short* __restrict__ w2e, float* __restrict__ bias1,
    float* __restrict__ bias2)
{
  int i = blockIdx.x * 256 + threadIdx.x;
  if (i < 576 * 160) {
    int rp = i / 160, k = i - rp * 160;
    int kk = rp >> 6, cc = rp & 63;
    int o = cc * 9 + kk;
    float s = gA[o] * rsqrtf(vA[o] + EPSB);
    float v = 0.f;
    if (k < 147) {
      int c = k / 49, rem = k - c * 49, ki = rem / 7, kj = rem - ki * 7;
      v = w_att[(o * 3 + c) * 49 + ki * 7 + kj] * s;
    } else if (k == 147) {
      v = b_att[o] * s + beA[o] - mA[o] * s;
    }
    wAe[i] = bfc(v);
    return;
  }
  i -= 576 * 160;
  if (i < 64 * 576) {
    int o = i / 576, kp = i - o * 576;
    int kk = kp >> 6, cc = kp & 63;
    float s = g1[o] * rsqrtf(v1[o] + EPSB);
    w1e[i] = bfc(w1[o * 576 + cc * 9 + kk] * s);
    return;
  }
  i -= 64 * 576;
  if (i < 64 * 576) {
    int o = i / 576, r = i - o * 576, kk = r >> 6, c = r & 63;
    float s = g2[o] * rsqrtf(v2[o] + EPSB);
    w2e[i] = bfc(w2[(o * 64 + c) * 9 + kk] * s);
    return;
  }
  i -= 64 * 576;
  if (i < 64) {
    float s = g1[i] * rsqrtf(v1[i] + EPSB);
    bias1[i] = b1[i] * s + be1[i] - m1[i] * s;
  } else if (i < 128) {
    int o = i - 64;
    float s = g2[o] * rsqrtf(v2[o] + EPSB);
    bias2[o] = b2[o] * s + be2[o] - m2[o] * s;
  }
}

// ---------------- K12 ----------------
__global__ __launch_bounds__(512, 4) void k12_kernel(
    const float* __restrict__ new_xyz, const float* __restrict__ feature,
    const unsigned short* __restrict__ wAe, const unsigned short* __restrict__ w1e,
    const float* __restrict__ bias1, unsigned short* __restrict__ h1g)
{
  // LDS (64256 B total, 2 blocks/CU):
  //  B1 [64][168] @0 (21504) | feat [3][66][64] @21504 (25344) | B2 [64][136] @46848 (17408)
  //  xyzb [23][72] (3312 B) + lut[160] alias B2.
  __shared__ __align__(16) unsigned char smem[64256];
  unsigned short* B1p   = (unsigned short*)smem;
  unsigned short* featp = (unsigned short*)(smem + 21504);
  unsigned short* B2p   = (unsigned short*)(smem + 46848);
  unsigned short* xyzb  = B2p;
  int* lut              = (int*)(smem + 46848 + 3312);

  const int bx = blockIdx.x;
  const int x0 = bx * 64;
  const int y  = blockIdx.y;
  const int n  = blockIdx.z;
  const int tid = threadIdx.x;
  const int lane = tid & 63;
  const int wv = tid >> 6;
  const int r16 = lane & 15;
  const int kq = (lane >> 4) & 3;
  const int l32 = lane & 31;
  const int hi = lane >> 5;
  const int wrow = wv & 3, wcol = wv >> 2;
  const int wh = wrow >> 1;
  const bool xedge = (bx == 0) || (bx == 7);

  // ---- stage new_xyz rows (c,ki) 0..20, width 70 (halo 3) ----
  for (int row = wv; row < 21; row += 8) {
    int c = (row >= 14) ? 2 : (row >= 7 ? 1 : 0);
    int ki = row - c * 7;
    int yy = y + ki - 3;
    bool rowok = (unsigned)yy < 64u;
    unsigned short* dst = xyzb + row * 72;
    if (rowok && !xedge) {
      const float* src = new_xyz + ((n * 3 + c) * 64 + yy) * 512 + (x0 - 3);
      dst[lane] = bfc(src[lane]);
      if (lane < 6) dst[64 + lane] = bfc(src[64 + lane]);
    } else {
      const float* src = new_xyz + ((n * 3 + c) * 64 + yy) * 512;
#pragma unroll
      for (int seg = 0; seg < 2; ++seg) {
        int xx = lane + seg * 64;
        if (xx < 70) {
          int xg = x0 + xx - 3;
          float v = (rowok && (unsigned)xg < 512u) ? src[xg] : 0.f;
          dst[xx] = bfc(v);
        }
      }
    }
  }
  if (tid < 72) { xyzb[21 * 72 + tid] = 0; xyzb[22 * 72 + tid] = 0x3F80; }
  else if (tid >= 128 && tid < 288) {
    int k = tid - 128;
    int off;
    if (k < 147) { int c = k / 49, rem = k - c * 49, ki = rem / 7, kj = rem - ki * 7; off = (c * 7 + ki) * 72 + kj; }
    else if (k == 147) off = 22 * 72;
    else off = 21 * 72;
    lut[k] = off;
  }
  __syncthreads();   // xyzb + lut ready

  // ---- build im2col B1 (reads xyzb/lut) ----
  {
    int p = tid >> 3, q = tid & 7;
    unsigned short* brow = B1p + p * 168;
#pragma unroll
    for (int j = 0; j < 5; ++j) {
      int k = (q * 5 + j) * 4;
      int o0 = lut[k], o1 = lut[k + 1], o2 = lut[k + 2], o3 = lut[k + 3];
      uint2 w;
      w.x = (unsigned int)xyzb[o0 + p] | ((unsigned int)xyzb[o1 + p] << 16);
      w.y = (unsigned int)xyzb[o2 + p] | ((unsigned int)xyzb[o3 + p] << 16);
      *(uint2*)(brow + k) = w;
    }
  }

  // ---- stage feature tile (overlaps B1 build), swizzled [r][xx][(c+4xx)&63] ----
  if (!xedge) {
    const int l16 = tid & 15;
    const int rp_ = tid >> 4;          // 0..31
    float4 va[3], vb[3];
#pragma unroll
    for (int pass = 0; pass < 3; ++pass) {
      int rp = pass * 32 + rp_;        // 0..95: r = rp>>5, c = (rp&31)*2
      int r = rp >> 5, c = (rp & 31) * 2;
      int yy = y + r - 1;
      bool ok = (unsigned)yy < 64u;
      const float* base = feature + ((n * 64 + c) * 64 + yy) * 512 + x0 + l16 * 4;
      float4 z = {0.f, 0.f, 0.f, 0.f};
      va[pass] = z; vb[pass] = z;
      if (ok) { va[pass] = *(const float4*)base; vb[pass] = *(const float4*)(base + 64 * 512); }
    }
#pragma unroll
    for (int pass = 0; pass < 3; ++pass) {
      int rp = pass * 32 + rp_;
      int r = rp >> 5, c = (rp & 31) * 2;
      int xx = l16 * 4 + 1;
      unsigned short* fb = featp + (r * 66) * 64;
      *(unsigned int*)&fb[(xx    ) * 64 + ((c + 4 * (xx    )) & 63)] = pk2(va[pass].x, vb[pass].x);
      *(unsigned int*)&fb[(xx + 1) * 64 + ((c + 4 * (xx + 1)) & 63)] = pk2(va[pass].y, vb[pass].y);
      *(unsigned int*)&fb[(xx + 2) * 64 + ((c + 4 * (xx + 2)) & 63)] = pk2(va[pass].z, vb[pass].z);
      *(unsigned int*)&fb[(xx + 3) * 64 + ((c + 4 * (xx + 3)) & 63)] = pk2(va[pass].w, vb[pass].w);
    }
    if (tid < 192) {
      int rp = tid >> 1, side = tid & 1;
      int r = rp >> 5, c = (rp & 31) * 2;
      int yy = y + r - 1;
      int xx = side ? 65 : 0;
      int xg = x0 + (side ? 64 : -1);
      float v0 = 0.f, v1 = 0.f;
      if ((unsigned)yy < 64u && (unsigned)xg < 512u) {
        const float* bp = feature + ((n * 64 + c) * 64 + yy) * 512 + xg;
        v0 = bp[0]; v1 = bp[64 * 512];
      }
      *(unsigned int*)&featp[(r * 66 + xx) * 64 + ((c + 4 * xx) & 63)] = pk2(v0, v1);
    }
  } else {
    for (int row = wv; row < 192; row += 8) {
      int c = row & 63, r = row >> 6;
      int yy = y + r - 1;
      bool rowok = (unsigned)yy < 64u;
      const float* src = feature + ((n * 64 + c) * 64 + yy) * 512;
#pragma unroll
      for (int seg = 0; seg < 2; ++seg) {
        int xx = lane + seg * 64;
        if (xx < 66) {
          int xg = x0 + xx - 1;
          float v = (rowok && (unsigned)xg < 512u) ? src[xg] : 0.f;
          featp[(r * 66 + xx) * 64 + ((c + 4 * xx) & 63)] = bfc(v);
        }
      }
    }
  }
  __syncthreads();   // B1 + feat ready; xyzb/lut dead

  const int p32 = 32 * wcol + l32;
  const int ccq = (wrow & 1) * 32;
  const unsigned short* Bp1 = B1p + p32 * 168 + hi * 8;

  // ---- persistent GEMM1 B-fragments: chunk-invariant, load ONCE ----
  bf16x8 bFr[10];
#pragma unroll
  for (int j = 0; j < 10; ++j) bFr[j] = *(const bf16x8*)(Bp1 + j * 16);

  f32x4 acc2[2];
#pragma unroll
  for (int i = 0; i < 2; ++i) acc2[i] = {0.f, 0.f, 0.f, 0.f};

#pragma unroll
  for (int c = 0; c < 4; ++c) {
    // ---- GEMM2 A-frags: issue early (global), consumed after bar2 ----
    bf16x8 a2f[4];
    const unsigned short* A2p = w1e + (16 * wrow + r16) * 576 + c * 128 + kq * 8;
#pragma unroll
    for (int kst = 0; kst < 4; ++kst) a2f[kst] = *(const bf16x8*)(A2p + kst * 32);

    // ---- GEMM1 chunk: {5 A-loads, 5 MFMA} x2, B from persistent regs ----
    f32x16 acc1;
#pragma unroll
    for (int i = 0; i < 16; ++i) acc1[i] = 0.f;
    const unsigned short* Ap = wAe + (c * 128 + wrow * 32 + l32) * 160 + hi * 8;
    bf16x8 aF[5];
#pragma unroll
    for (int j = 0; j < 5; ++j) aF[j] = *(const bf16x8*)(Ap + j * 16);
#pragma unroll
    for (int j = 0; j < 5; ++j) acc1 = __builtin_amdgcn_mfma_f32_32x32x16_bf16(aF[j], bFr[j], acc1, 0, 0, 0);
#pragma unroll
    for (int j = 0; j < 5; ++j) aF[j] = *(const bf16x8*)(Ap + 80 + j * 16);
#pragma unroll
    for (int j = 0; j < 5; ++j) acc1 = __builtin_amdgcn_mfma_f32_32x32x16_bf16(aF[j], bFr[5 + j], acc1, 0, 0, 0);

    // ---- gate: att = sigmoid(acc1); B2[p][k] = att * feat ----
    int kkA = 2 * c + wh;
    int di = (kkA >= 6) ? 2 : (kkA >= 3 ? 1 : 0);
    int dj = kkA - 3 * di;
    int xxp = p32 + dj;
    const unsigned short* frow = featp + (di * 66 + xxp) * 64;
    unsigned short* brow2 = B2p + p32 * 136 + wrow * 32;
#pragma unroll
    for (int q = 0; q < 4; ++q) {
      int r0 = 8 * q + 4 * hi;
      uint2 fv = *(const uint2*)(frow + ((ccq + r0 + 4 * xxp) & 63));
      float s0 = sigm(acc1[4 * q + 0]) * lo16f(fv.x);
      float s1 = sigm(acc1[4 * q + 1]) * hi16f(fv.x);
      float s2 = sigm(acc1[4 * q + 2]) * lo16f(fv.y);
      float s3 = sigm(acc1[4 * q + 3]) * hi16f(fv.y);
      uint2 w; w.x = pk2(s0, s1); w.y = pk2(s2, s3);
      *(uint2*)(brow2 + r0) = w;
    }

    __syncthreads();   // B2 chunk written

    // ---- GEMM2: stage 8 B-frags to regs, barrier, then MFMA from regs ----
    bf16x8 b2f[8];
#pragma unroll
    for (int kst = 0; kst < 4; ++kst)
#pragma unroll
      for (int pf = 0; pf < 2; ++pf)
        b2f[kst * 2 + pf] = *(const bf16x8*)(B2p + (32 * wcol + 16 * pf + r16) * 136 + kst * 32 + kq * 8);

    __syncthreads();   // B2 reads drained; next gate-write safe

#pragma unroll
    for (int kst = 0; kst < 4; ++kst) {
      acc2[0] = __builtin_amdgcn_mfma_f32_16x16x32_bf16(a2f[kst], b2f[kst * 2 + 0], acc2[0], 0, 0, 0);
      acc2[1] = __builtin_amdgcn_mfma_f32_16x16x32_bf16(a2f[kst], b2f[kst * 2 + 1], acc2[1], 0, 0, 0);
    }
  }

  // ---- tail chunk: rows 512..575 (GEMM1 by waves wrow<2) ----
  {
    bf16x8 a2f[2];
    const unsigned short* A2p = w1e + (16 * wrow + r16) * 576 + 512 + kq * 8;
    a2f[0] = *(const bf16x8*)(A2p);
    a2f[1] = *(const bf16x8*)(A2p + 32);

    if (wrow < 2) {
      f32x16 acc1;
#pragma unroll
      for (int i = 0; i < 16; ++i) acc1[i] = 0.f;
      const unsigned short* Ap = wAe + (512 + wrow * 32 + l32) * 160 + hi * 8;
      bf16x8 aF[5];
#pragma unroll
      for (int j = 0; j < 5; ++j) aF[j] = *(const bf16x8*)(Ap + j * 16);
#pragma unroll
      for (int j = 0; j < 5; ++j) acc1 = __builtin_amdgcn_mfma_f32_32x32x16_bf16(aF[j], bFr[j], acc1, 0, 0, 0);
#pragma unroll
      for (int j = 0; j < 5; ++j) aF[j] = *(const bf16x8*)(Ap + 80 + j * 16);
#pragma unroll
      for (int j = 0; j < 5; ++j) acc1 = __builtin_amdgcn_mfma_f32_32x32x16_bf16(aF[j], bFr[5 + j], acc1, 0, 0, 0);
      int xxp = p32 + 2;                                 // kk=8 -> di=2, dj=2
      const unsigned short* frow = featp + (2 * 66 + xxp) * 64;
      unsigned short* brow2 = B2p + p32 * 136 + wrow * 32;
#pragma unroll
      for (int q = 0; q < 4; ++q) {
        int r0 = 8 * q + 4 * hi;
        uint2 fv = *(const uint2*)(frow + ((ccq + r0 + 4 * xxp) & 63));
        float s0 = sigm(acc1[4 * q + 0]) * lo16f(fv.x);
        float s1 = sigm(acc1[4 * q + 1]) * hi16f(fv.x);
        float s2 = sigm(acc1[4 * q + 2]) * lo16f(fv.y);
        float s3 = sigm(acc1[4 * q + 3]) * hi16f(fv.y);
        uint2 w; w.x = pk2(s0, s1); w.y = pk2(s2, s3);
        *(uint2*)(brow2 + r0) = w;
      }
    }
    __syncthreads();
    bf16x8 b2f[4];
#pragma unroll
    for (int kst = 0; kst < 2; ++kst)
#pragma unroll
      for (int pf = 0; pf < 2; ++pf)
        b2f[kst * 2 + pf] = *(const bf16x8*)(B2p + (32 * wcol + 16 * pf + r16) * 136 + kst * 32 + kq * 8);
    __syncthreads();
#pragma unroll
    for (int kst = 0; kst < 2; ++kst) {
      acc2[0] = __builtin_amdgcn_mfma_f32_16x16x32_bf16(a2f[kst], b2f[kst * 2 + 0], acc2[0], 0, 0, 0);
      acc2[1] = __builtin_amdgcn_mfma_f32_16x16x32_bf16(a2f[kst], b2f[kst * 2 + 1], acc2[1], 0, 0, 0);
    }
  }

  // ---- epilogue: h1 = relu(acc2 + bias1), transpose via B2 region ----
  const int ccb = 16 * wrow + 4 * kq;
  float b1v0 = bias1[ccb], b1v1 = bias1[ccb + 1], b1v2 = bias1[ccb + 2], b1v3 = bias1[ccb + 3];
#pragma unroll
  for (int pf = 0; pf < 2; ++pf) {
    int p = 32 * wcol + 16 * pf + r16;
    uint2 w;
    w.x = pk2(fmaxf(acc2[pf][0] + b1v0, 0.f), fmaxf(acc2[pf][1] + b1v1, 0.f));
    w.y = pk2(fmaxf(acc2[pf][2] + b1v2, 0.f), fmaxf(acc2[pf][3] + b1v3, 0.f));
    *(uint2*)(B2p + p * 136 + ccb) = w;
  }
  __syncthreads();
  {
    int p = tid >> 3, c0 = (tid & 7) * 8;
    uint4 v = *(const uint4*)(B2p + p * 136 + c0);
    *(uint4*)(h1g + (((n * 64 + y) * 512) + x0) * 64 + p * 64 + c0) = v;
  }
}

// ---------------- K3: 3x3 conv 64->64 + BN + ReLU + residual ----------------
__global__ __launch_bounds__(256) void k3_kernel(
    const unsigned short* __restrict__ h1g, const float* __restrict__ feature,
    const unsigned short* __restrict__ w2e, const float* __restrict__ bias2,
    float* __restrict__ out)
{
  __shared__ unsigned short s_h1[3][66][72];

  const int x0 = blockIdx.x * 64;
  const int y  = blockIdx.y;
  const int n  = blockIdx.z;
  const int tid = threadIdx.x;
  const int lane = tid & 63;
  const int wv = tid >> 6;
  const int r16 = lane & 15;
  const int kq = lane >> 4;

  // ---- preload ALL 18 A-fragments (L2-resident weights) ----
  const unsigned short* Ap = w2e + (16 * wv + r16) * 576 + kq * 8;
  bf16x8 af[18];
#pragma unroll
  for (int kst = 0; kst < 18; ++kst) af[kst] = *(const bf16x8*)(Ap + kst * 32);

  for (int idx = tid; idx < 3 * 66 * 16; idx += 256) {
    int r = idx / (66 * 16), rem = idx - r * 66 * 16, xx = rem >> 4, c0 = (rem & 15) << 2;
    int yy = y + r - 1, xg = x0 + xx - 1;
    uint2 v; v.x = 0u; v.y = 0u;
    if (yy >= 0 && yy < 64 && xg >= 0 && xg < 512)
      v = *(const uint2*)(h1g + (((n * 64 + yy) * 512) + xg) * 64 + c0);
    *(uint2*)(&s_h1[r][xx][c0]) = v;
  }
  __syncthreads();

  f32x4 acc[4];
#pragma unroll
  for (int i = 0; i < 4; ++i) acc[i] = {0.f, 0.f, 0.f, 0.f};

#pragma unroll 2
  for (int kst = 0; kst < 18; ++kst) {
    int kk = kst >> 1, di = kk / 3, dj = kk - di * 3;
    int chalf = (kst & 1) << 5;
#pragma unroll
    for (int pf = 0; pf < 4; ++pf) {
      bf16x8 b = *(const bf16x8*)(&s_h1[di][pf * 16 + r16 + dj][chalf + kq * 8]);
      acc[pf] = __builtin_amdgcn_mfma_f32_16x16x32_bf16(af[kst], b, acc[pf], 0, 0, 0);
    }
  }

#pragma unroll
  for (int pf = 0; pf < 4; ++pf) {
    int p = pf * 16 + r16;
#pragma unroll
    for (int r = 0; r < 4; ++r) {
      int ch = 16 * wv + kq * 4 + r;
      int off = (((n * 64 + ch) * 64) + y) * 512 + x0 + p;
      out[off] = fmaxf(acc[pf][r] + bias2[ch], 0.f) + feature[off];
    }
  }
}

// ---------------- launch ----------------
extern "C" void kernel_launch(void* const* d_in, const int* in_sizes, int n_in,
                              void* d_out, int out_size, void* d_ws, size_t ws_size,
                              hipStream_t stream)
{
  const float* new_xyz = (const float*)d_in[1];
  const float* feature = (const float*)d_in[2];
  const float* w_att = (const float*)d_in[3];
  const float* b_att = (const float*)d_in[4];
  const float* gA  = (const float*)d_in[5];
  const float* beA = (const float*)d_in[6];
  const float* mA  = (const float*)d_in[7];
  const float* vA  = (const float*)d_in[8];
  const float* w1  = (const float*)d_in[9];
  const float* b1  = (const float*)d_in[10];
  const float* g1  = (const float*)d_in[11];
  const float* be1 = (const float*)d_in[12];
  const float* m1  = (const float*)d_in[13];
  const float* v1  = (const float*)d_in[14];
  const float* w2  = (const float*)d_in[15];
  const float* b2  = (const float*)d_in[16];
  const float* g2  = (const float*)d_in[17];
  const float* be2 = (const float*)d_in[18];
  const float* m2  = (const float*)d_in[19];
  const float* v2  = (const float*)d_in[20];

  char* ws = (char*)d_ws;
  unsigned short* wAe = (unsigned short*)(ws);             // 576*160*2 = 184320
  unsigned short* w1e = (unsigned short*)(ws + 184320);    // 64*576*2  =  73728
  unsigned short* w2e = (unsigned short*)(ws + 258048);    // 64*576*2  =  73728
  float* bias1 = (float*)(ws + 331776);                    // 256
  float* bias2 = (float*)(ws + 332032);                    // 256
  unsigned short* h1g = (unsigned short*)(ws + 335872);    // 16 MB

  prep_kernel<<<649, 256, 0, stream>>>(w_att, b_att, gA, beA, mA, vA,
                                       w1, b1, g1, be1, m1, v1,
                                       w2, b2, g2, be2, m2, v2,
                                       wAe, w1e, w2e, bias1, bias2);
  k12_kernel<<<dim3(8, 64, 4), 512, 0, stream>>>(new_xyz, feature, wAe, w1e, bias1, h1g);
  k3_kernel<<<dim3(8, 64, 4), 256, 0, stream>>>(h1g, feature, w2e, bias2, (float*)d_out);
}

// Round 6
// 180.068 us; speedup vs baseline: 1.1941x; 1.1941x over previous
//
#include <hip/hip_runtime.h>

#define EPSB 1e-5f

typedef __bf16 bf16x8 __attribute__((ext_vector_type(8)));
typedef float f32x4 __attribute__((ext_vector_type(4)));
typedef float f32x16 __attribute__((ext_vector_type(16)));

__device__ __forceinline__ unsigned short bfc(float v) {
  __bf16 h = (__bf16)v;
  return __builtin_bit_cast(unsigned short, h);
}
__device__ __forceinline__ unsigned int pk2(float a, float b) {
  return (unsigned int)bfc(a) | ((unsigned int)bfc(b) << 16);
}
__device__ __forceinline__ float lo16f(unsigned int u) {
  union { unsigned int u; float f; } v; v.u = u << 16; return v.f;
}
__device__ __forceinline__ float hi16f(unsigned int u) {
  union { unsigned int u; float f; } v; v.u = u & 0xFFFF0000u; return v.f;
}
__device__ __forceinline__ float sigm(float x) {
  float e = __builtin_amdgcn_exp2f(-x * 1.4426950408889634f);
  return __builtin_amdgcn_rcpf(1.0f + e);
}

// ---------------- prep: fold BN into bf16 weights ----------------
__global__ void prep_kernel(
    const float* __restrict__ w_att, const float* __restrict__ b_att,
    const float* __restrict__ gA, const float* __restrict__ beA,
    const float* __restrict__ mA, const float* __restrict__ vA,
    const float* __restrict__ w1, const float* __restrict__ b1,
    const float* __restrict__ g1, const float* __restrict__ be1,
    const float* __restrict__ m1, const float* __restrict__ v1,
    const float* __restrict__ w2, const float* __restrict__ b2,
    const float* __restrict__ g2, const float* __restrict__ be2,
    const float* __restrict__ m2, const float* __restrict__ v2,
    unsigned short* __restrict__ wAe, unsigned short* __restrict__ w1e,
    unsigned short* __restrict__ w2e, float* __restrict__ bias1,
    float* __restrict__ bias2)
{
  int i = blockIdx.x * 256 + threadIdx.x;
  if (i < 576 * 160) {
    int rp = i / 160, k = i - rp * 160;
    int kk = rp >> 6, cc = rp & 63;
    int o = cc * 9 + kk;
    float s = gA[o] * rsqrtf(vA[o] + EPSB);
    float v = 0.f;
    if (k < 147) {
      int c = k / 49, rem = k - c * 49, ki = rem / 7, kj = rem - ki * 7;
      v = w_att[(o * 3 + c) * 49 + ki * 7 + kj] * s;
    } else if (k == 147) {
      v = b_att[o] * s + beA[o] - mA[o] * s;
    }
    wAe[i] = bfc(v);
    return;
  }
  i -= 576 * 160;
  if (i < 64 * 576) {
    int o = i / 576, kp = i - o * 576;
    int kk = kp >> 6, cc = kp & 63;
    float s = g1[o] * rsqrtf(v1[o] + EPSB);
    w1e[i] = bfc(w1[o * 576 + cc * 9 + kk] * s);
    return;
  }
  i -= 64 * 576;
  if (i < 64 * 576) {
    int o = i / 576, r = i - o * 576, kk = r >> 6, c = r & 63;
    float s = g2[o] * rsqrtf(v2[o] + EPSB);
    w2e[i] = bfc(w2[(o * 64 + c) * 9 + kk] * s);
    return;
  }
  i -= 64 * 576;
  if (i < 64) {
    float s = g1[i] * rsqrtf(v1[i] + EPSB);
    bias1[i] = b1[i] * s + be1[i] - m1[i] * s;
  } else if (i < 128) {
    int o = i - 64;
    float s = g2[o] * rsqrtf(v2[o] + EPSB);
    bias2[o] = b2[o] * s + be2[o] - m2[o] * s;
  }
}

// ---------------- K0: feature [N][C][H][W] f32 -> featT [N][H][W][C] bf16 ----------------
__global__ __launch_bounds__(256) void k0_kernel(
    const float* __restrict__ feature, unsigned short* __restrict__ featT)
{
  __shared__ unsigned short t[64][76];   // [x][c], 152B rows
  const int x0 = blockIdx.x * 64, y = blockIdx.y, n = blockIdx.z;
  const int tid = threadIdx.x;
#pragma unroll
  for (int k = 0; k < 4; ++k) {
    int q = tid + k * 256;               // 0..1023: c = q>>4, xq = q&15
    int c = q >> 4, xq = q & 15;
    float4 v = *(const float4*)(feature + ((n * 64 + c) * 64 + y) * 512 + x0 + xq * 4);
    int xx = xq * 4;
    t[xx][c] = bfc(v.x); t[xx + 1][c] = bfc(v.y); t[xx + 2][c] = bfc(v.z); t[xx + 3][c] = bfc(v.w);
  }
  __syncthreads();
#pragma unroll
  for (int k = 0; k < 2; ++k) {
    int q = tid + k * 256;               // 0..511: p = q>>3, c0 = (q&7)*8
    int p = q >> 3, c0 = (q & 7) * 8;
    uint2 v0 = *(const uint2*)(&t[p][c0]);
    uint2 v1 = *(const uint2*)(&t[p][c0 + 4]);
    unsigned short* dst = featT + ((n * 64 + y) * 512 + x0 + p) * 64 + c0;
    *(uint2*)dst = v0;
    *(uint2*)(dst + 4) = v1;
  }
}

// ---------------- K12: attention GEMM (32x32) + sigmoid gate + 1x1 conv ----------------
__global__ __launch_bounds__(512, 6) void k12_kernel(
    const float* __restrict__ new_xyz, const unsigned short* __restrict__ featT,
    const unsigned short* __restrict__ wAe, const unsigned short* __restrict__ w1e,
    const float* __restrict__ bias1, unsigned short* __restrict__ h1g)
{
  // LDS 38912 B total: B1 [64][168] @0 (21504) | B2 [64][136] @21504 (17408)
  // xyzb [23][72] (3312 B) + lut[160] alias B2.
  __shared__ __align__(16) unsigned char smem[38912];
  unsigned short* B1p  = (unsigned short*)smem;
  unsigned short* B2p  = (unsigned short*)(smem + 21504);
  unsigned short* xyzb = B2p;
  int* lut             = (int*)(smem + 21504 + 3312);

  const int bx = blockIdx.x;
  const int x0 = bx * 64;
  const int y  = blockIdx.y;
  const int n  = blockIdx.z;
  const int tid = threadIdx.x;
  const int lane = tid & 63;
  const int wv = tid >> 6;
  const int r16 = lane & 15;
  const int kq = (lane >> 4) & 3;
  const int l32 = lane & 31;
  const int hi = lane >> 5;
  const int wrow = wv & 3, wcol = wv >> 2;
  const int wh = wrow >> 1;
  const bool xedge = (bx == 0) || (bx == 7);

  // ---- stage new_xyz rows (c,ki) 0..20, width 70 (halo 3) ----
  for (int row = wv; row < 21; row += 8) {
    int c = (row >= 14) ? 2 : (row >= 7 ? 1 : 0);
    int ki = row - c * 7;
    int yy = y + ki - 3;
    bool rowok = (unsigned)yy < 64u;
    unsigned short* dst = xyzb + row * 72;
    if (rowok && !xedge) {
      const float* src = new_xyz + ((n * 3 + c) * 64 + yy) * 512 + (x0 - 3);
      dst[lane] = bfc(src[lane]);
      if (lane < 6) dst[64 + lane] = bfc(src[64 + lane]);
    } else {
      const float* src = new_xyz + ((n * 3 + c) * 64 + yy) * 512;
#pragma unroll
      for (int seg = 0; seg < 2; ++seg) {
        int xx = lane + seg * 64;
        if (xx < 70) {
          int xg = x0 + xx - 3;
          float v = (rowok && (unsigned)xg < 512u) ? src[xg] : 0.f;
          dst[xx] = bfc(v);
        }
      }
    }
  }
  if (tid < 72) { xyzb[21 * 72 + tid] = 0; xyzb[22 * 72 + tid] = 0x3F80; }
  else if (tid >= 128 && tid < 288) {
    int k = tid - 128;
    int off;
    if (k < 147) { int c = k / 49, rem = k - c * 49, ki = rem / 7, kj = rem - ki * 7; off = (c * 7 + ki) * 72 + kj; }
    else if (k == 147) off = 22 * 72;
    else off = 21 * 72;
    lut[k] = off;
  }
  __syncthreads();   // xyzb + lut ready

  // ---- build im2col B1 ----
  {
    int p = tid >> 3, q = tid & 7;
    unsigned short* brow = B1p + p * 168;
#pragma unroll
    for (int j = 0; j < 5; ++j) {
      int k = (q * 5 + j) * 4;
      int o0 = lut[k], o1 = lut[k + 1], o2 = lut[k + 2], o3 = lut[k + 3];
      uint2 w;
      w.x = (unsigned int)xyzb[o0 + p] | ((unsigned int)xyzb[o1 + p] << 16);
      w.y = (unsigned int)xyzb[o2 + p] | ((unsigned int)xyzb[o3 + p] << 16);
      *(uint2*)(brow + k) = w;
    }
  }
  __syncthreads();   // B1 ready; xyzb/lut dead (B2 free)

  const int p32 = 32 * wcol + l32;
  const int ccq = (wrow & 1) * 32;
  const unsigned short* Bp1 = B1p + p32 * 168 + hi * 8;

  f32x4 acc2[2];
#pragma unroll
  for (int i = 0; i < 2; ++i) acc2[i] = {0.f, 0.f, 0.f, 0.f};

#pragma unroll
  for (int c = 0; c < 4; ++c) {
    const int kkA = 2 * c + wh;
    const int di = (kkA >= 6) ? 2 : (kkA >= 3 ? 1 : 0);
    const int dj = kkA - 3 * di;

    // ---- prefetch gate feature values (global, L2) ----
    int yy = y + di - 1, xg = x0 + p32 + dj - 1;
    bool ok = ((unsigned)yy < 64u) && ((unsigned)xg < 512u);
    const unsigned short* fT = featT + ((n * 64 + yy) * 512 + xg) * 64 + ccq + 4 * hi;
    uint2 fv[4];
#pragma unroll
    for (int q = 0; q < 4; ++q) {
      uint2 z; z.x = 0u; z.y = 0u;
      fv[q] = ok ? *(const uint2*)(fT + 8 * q) : z;
    }

    // ---- GEMM1 chunk: rows c*128 + wrow*32, K=160, rolling loads ----
    f32x16 acc1;
#pragma unroll
    for (int i = 0; i < 16; ++i) acc1[i] = 0.f;
    const unsigned short* Ap = wAe + (c * 128 + wrow * 32 + l32) * 160 + hi * 8;
#pragma unroll
    for (int j = 0; j < 10; ++j) {
      bf16x8 a = *(const bf16x8*)(Ap + j * 16);
      bf16x8 b = *(const bf16x8*)(Bp1 + j * 16);
      acc1 = __builtin_amdgcn_mfma_f32_32x32x16_bf16(a, b, acc1, 0, 0, 0);
    }

    // ---- gate ----
    unsigned short* brow2 = B2p + p32 * 136 + wrow * 32;
#pragma unroll
    for (int q = 0; q < 4; ++q) {
      int r0 = 8 * q + 4 * hi;
      float s0 = sigm(acc1[4 * q + 0]) * lo16f(fv[q].x);
      float s1 = sigm(acc1[4 * q + 1]) * hi16f(fv[q].x);
      float s2 = sigm(acc1[4 * q + 2]) * lo16f(fv[q].y);
      float s3 = sigm(acc1[4 * q + 3]) * hi16f(fv[q].y);
      uint2 w; w.x = pk2(s0, s1); w.y = pk2(s2, s3);
      *(uint2*)(brow2 + r0) = w;
    }
    __syncthreads();   // B2 chunk written

    // ---- GEMM2 partial, K=128 ----
    const unsigned short* A2p = w1e + (16 * wrow + r16) * 576 + c * 128 + kq * 8;
#pragma unroll
    for (int kst = 0; kst < 4; ++kst) {
      bf16x8 a  = *(const bf16x8*)(A2p + kst * 32);
      bf16x8 b0 = *(const bf16x8*)(B2p + (32 * wcol + r16) * 136 + kst * 32 + kq * 8);
      bf16x8 b1 = *(const bf16x8*)(B2p + (32 * wcol + 16 + r16) * 136 + kst * 32 + kq * 8);
      acc2[0] = __builtin_amdgcn_mfma_f32_16x16x32_bf16(a, b0, acc2[0], 0, 0, 0);
      acc2[1] = __builtin_amdgcn_mfma_f32_16x16x32_bf16(a, b1, acc2[1], 0, 0, 0);
    }
    __syncthreads();   // B2 reads drained before next gate write
  }

  // ---- tail chunk: rows 512..575 (kk=8: di=2, dj=2), GEMM1 by wrow<2 ----
  {
    if (wrow < 2) {
      int yy = y + 1, xg = x0 + p32 + 1;
      bool ok = ((unsigned)yy < 64u) && ((unsigned)xg < 512u);
      const unsigned short* fT = featT + ((n * 64 + yy) * 512 + xg) * 64 + ccq + 4 * hi;
      uint2 fv[4];
#pragma unroll
      for (int q = 0; q < 4; ++q) {
        uint2 z; z.x = 0u; z.y = 0u;
        fv[q] = ok ? *(const uint2*)(fT + 8 * q) : z;
      }
      f32x16 acc1;
#pragma unroll
      for (int i = 0; i < 16; ++i) acc1[i] = 0.f;
      const unsigned short* Ap = wAe + (512 + wrow * 32 + l32) * 160 + hi * 8;
#pragma unroll
      for (int j = 0; j < 10; ++j) {
        bf16x8 a = *(const bf16x8*)(Ap + j * 16);
        bf16x8 b = *(const bf16x8*)(Bp1 + j * 16);
        acc1 = __builtin_amdgcn_mfma_f32_32x32x16_bf16(a, b, acc1, 0, 0, 0);
      }
      unsigned short* brow2 = B2p + p32 * 136 + wrow * 32;
#pragma unroll
      for (int q = 0; q < 4; ++q) {
        int r0 = 8 * q + 4 * hi;
        float s0 = sigm(acc1[4 * q + 0]) * lo16f(fv[q].x);
        float s1 = sigm(acc1[4 * q + 1]) * hi16f(fv[q].x);
        float s2 = sigm(acc1[4 * q + 2]) * lo16f(fv[q].y);
        float s3 = sigm(acc1[4 * q + 3]) * hi16f(fv[q].y);
        uint2 w; w.x = pk2(s0, s1); w.y = pk2(s2, s3);
        *(uint2*)(brow2 + r0) = w;
      }
    }
    __syncthreads();
    const unsigned short* A2p = w1e + (16 * wrow + r16) * 576 + 512 + kq * 8;
#pragma unroll
    for (int kst = 0; kst < 2; ++kst) {
      bf16x8 a  = *(const bf16x8*)(A2p + kst * 32);
      bf16x8 b0 = *(const bf16x8*)(B2p + (32 * wcol + r16) * 136 + kst * 32 + kq * 8);
      bf16x8 b1 = *(const bf16x8*)(B2p + (32 * wcol + 16 + r16) * 136 + kst * 32 + kq * 8);
      acc2[0] = __builtin_amdgcn_mfma_f32_16x16x32_bf16(a, b0, acc2[0], 0, 0, 0);
      acc2[1] = __builtin_amdgcn_mfma_f32_16x16x32_bf16(a, b1, acc2[1], 0, 0, 0);
    }
    __syncthreads();   // B2 reads drained before epilogue writes
  }

  // ---- epilogue: h1 = relu(acc2 + bias1), transpose via B2 ----
  const int ccb = 16 * wrow + 4 * kq;
  float b1v0 = bias1[ccb], b1v1 = bias1[ccb + 1], b1v2 = bias1[ccb + 2], b1v3 = bias1[ccb + 3];
#pragma unroll
  for (int pf = 0; pf < 2; ++pf) {
    int p = 32 * wcol + 16 * pf + r16;
    uint2 w;
    w.x = pk2(fmaxf(acc2[pf][0] + b1v0, 0.f), fmaxf(acc2[pf][1] + b1v1, 0.f));
    w.y = pk2(fmaxf(acc2[pf][2] + b1v2, 0.f), fmaxf(acc2[pf][3] + b1v3, 0.f));
    *(uint2*)(B2p + p * 136 + ccb) = w;
  }
  __syncthreads();
  {
    int p = tid >> 3, c0 = (tid & 7) * 8;
    uint4 v = *(const uint4*)(B2p + p * 136 + c0);
    *(uint4*)(h1g + (((n * 64 + y) * 512) + x0) * 64 + p * 64 + c0) = v;
  }
}

// ---------------- K3: 3x3 conv 64->64 + BN + ReLU + residual ----------------
__global__ __launch_bounds__(256) void k3_kernel(
    const unsigned short* __restrict__ h1g, const float* __restrict__ feature,
    const unsigned short* __restrict__ w2e, const float* __restrict__ bias2,
    float* __restrict__ out)
{
  __shared__ unsigned short s_h1[3][66][72];

  const int x0 = blockIdx.x * 64;
  const int y  = blockIdx.y;
  const int n  = blockIdx.z;
  const int tid = threadIdx.x;
  const int lane = tid & 63;
  const int wv = tid >> 6;
  const int r16 = lane & 15;
  const int kq = lane >> 4;

  for (int idx = tid; idx < 3 * 66 * 16; idx += 256) {
    int r = idx / (66 * 16), rem = idx - r * 66 * 16, xx = rem >> 4, c0 = (rem & 15) << 2;
    int yy = y + r - 1, xg = x0 + xx - 1;
    uint2 v; v.x = 0u; v.y = 0u;
    if (yy >= 0 && yy < 64 && xg >= 0 && xg < 512)
      v = *(const uint2*)(h1g + (((n * 64 + yy) * 512) + xg) * 64 + c0);
    *(uint2*)(&s_h1[r][xx][c0]) = v;
  }
  __syncthreads();

  f32x4 acc[4];
#pragma unroll
  for (int i = 0; i < 4; ++i) acc[i] = {0.f, 0.f, 0.f, 0.f};

  const unsigned short* Ap = w2e + (16 * wv + r16) * 576 + kq * 8;
#pragma unroll 2
  for (int kst = 0; kst < 18; ++kst) {
    bf16x8 a = *(const bf16x8*)(Ap + kst * 32);
    int kk = kst >> 1, di = kk / 3, dj = kk - di * 3;
    int chalf = (kst & 1) << 5;
#pragma unroll
    for (int pf = 0; pf < 4; ++pf) {
      bf16x8 b = *(const bf16x8*)(&s_h1[di][pf * 16 + r16 + dj][chalf + kq * 8]);
      acc[pf] = __builtin_amdgcn_mfma_f32_16x16x32_bf16(a, b, acc[pf], 0, 0, 0);
    }
  }

#pragma unroll
  for (int pf = 0; pf < 4; ++pf) {
    int p = pf * 16 + r16;
#pragma unroll
    for (int r = 0; r < 4; ++r) {
      int ch = 16 * wv + kq * 4 + r;
      int off = (((n * 64 + ch) * 64) + y) * 512 + x0 + p;
      out[off] = fmaxf(acc[pf][r] + bias2[ch], 0.f) + feature[off];
    }
  }
}

// ---------------- launch ----------------
extern "C" void kernel_launch(void* const* d_in, const int* in_sizes, int n_in,
                              void* d_out, int out_size, void* d_ws, size_t ws_size,
                              hipStream_t stream)
{
  const float* new_xyz = (const float*)d_in[1];
  const float* feature = (const float*)d_in[2];
  const float* w_att = (const float*)d_in[3];
  const float* b_att = (const float*)d_in[4];
  const float* gA  = (const float*)d_in[5];
  const float* beA = (const float*)d_in[6];
  const float* mA  = (const float*)d_in[7];
  const float* vA  = (const float*)d_in[8];
  const float* w1  = (const float*)d_in[9];
  const float* b1  = (const float*)d_in[10];
  const float* g1  = (const float*)d_in[11];
  const float* be1 = (const float*)d_in[12];
  const float* m1  = (const float*)d_in[13];
  const float* v1  = (const float*)d_in[14];
  const float* w2  = (const float*)d_in[15];
  const float* b2  = (const float*)d_in[16];
  const float* g2  = (const float*)d_in[17];
  const float* be2 = (const float*)d_in[18];
  const float* m2  = (const float*)d_in[19];
  const float* v2  = (const float*)d_in[20];

  char* ws = (char*)d_ws;
  unsigned short* wAe = (unsigned short*)(ws);               // 576*160*2 = 184320
  unsigned short* w1e = (unsigned short*)(ws + 184320);      // 64*576*2  =  73728
  unsigned short* w2e = (unsigned short*)(ws + 258048);      // 64*576*2  =  73728
  float* bias1 = (float*)(ws + 331776);                      // 256
  float* bias2 = (float*)(ws + 332032);                      // 256
  unsigned short* h1g   = (unsigned short*)(ws + 335872);    // 16 MB
  unsigned short* featT = (unsigned short*)(ws + 335872 + 16777216);  // 16 MB

  prep_kernel<<<649, 256, 0, stream>>>(w_att, b_att, gA, beA, mA, vA,
                                       w1, b1, g1, be1, m1, v1,
                                       w2, b2, g2, be2, m2, v2,
                                       wAe, w1e, w2e, bias1, bias2);
  k0_kernel<<<dim3(8, 64, 4), 256, 0, stream>>>(feature, featT);
  k12_kernel<<<dim3(8, 64, 4), 512, 0, stream>>>(new_xyz, featT, wAe, w1e, bias1, h1g);
  k3_kernel<<<dim3(8, 64, 4), 256, 0, stream>>>(h1g, feature, w2e, bias2, (float*)d_out);
}

// Round 7
// 152.337 us; speedup vs baseline: 1.4114x; 1.1820x over previous
//
#include <hip/hip_runtime.h>

#define EPSB 1e-5f

typedef __bf16 bf16x8 __attribute__((ext_vector_type(8)));
typedef float f32x4 __attribute__((ext_vector_type(4)));
typedef float f32x16 __attribute__((ext_vector_type(16)));

__device__ __forceinline__ unsigned short bfc(float v) {
  __bf16 h = (__bf16)v;
  return __builtin_bit_cast(unsigned short, h);
}
__device__ __forceinline__ unsigned int pk2(float a, float b) {
  return (unsigned int)bfc(a) | ((unsigned int)bfc(b) << 16);
}
__device__ __forceinline__ float sigm(float x) {
  float e = __builtin_amdgcn_exp2f(-x * 1.4426950408889634f);
  return __builtin_amdgcn_rcpf(1.0f + e);
}

// ---------------- prep: fold BN into bf16 weights ----------------
__global__ void prep_kernel(
    const float* __restrict__ w_att, const float* __restrict__ b_att,
    const float* __restrict__ gA, const float* __restrict__ beA,
    const float* __restrict__ mA, const float* __restrict__ vA,
    const float* __restrict__ w1, const float* __restrict__ b1,
    const float* __restrict__ g1, const float* __restrict__ be1,
    const float* __restrict__ m1, const float* __restrict__ v1,
    const float* __restrict__ w2, const float* __restrict__ b2,
    const float* __restrict__ g2, const float* __restrict__ be2,
    const float* __restrict__ m2, const float* __restrict__ v2,
    unsigned short* __restrict__ wAe, unsigned short* __restrict__ w1e,
    unsigned short* __restrict__ w2e, float* __restrict__ bias1,
    float* __restrict__ bias2)
{
  int i = blockIdx.x * 256 + threadIdx.x;
  if (i < 576 * 160) {
    int rp = i / 160, k = i - rp * 160;
    int kk = rp >> 6, cc = rp & 63;
    int o = cc * 9 + kk;
    float s = gA[o] * rsqrtf(vA[o] + EPSB);
    float v = 0.f;
    if (k < 147) {
      int c = k / 49, rem = k - c * 49, ki = rem / 7, kj = rem - ki * 7;
      v = w_att[(o * 3 + c) * 49 + ki * 7 + kj] * s;
    } else if (k == 147) {
      v = b_att[o] * s + beA[o] - mA[o] * s;
    }
    wAe[i] = bfc(v);
    return;
  }
  i -= 576 * 160;
  if (i < 64 * 576) {
    int o = i / 576, kp = i - o * 576;
    int kk = kp >> 6, cc = kp & 63;
    float s = g1[o] * rsqrtf(v1[o] + EPSB);
    w1e[i] = bfc(w1[o * 576 + cc * 9 + kk] * s);
    return;
  }
  i -= 64 * 576;
  if (i < 64 * 576) {
    int o = i / 576, r = i - o * 576, kk = r >> 6, c = r & 63;
    float s = g2[o] * rsqrtf(v2[o] + EPSB);
    w2e[i] = bfc(w2[(o * 64 + c) * 9 + kk] * s);
    return;
  }
  i -= 64 * 576;
  if (i < 64) {
    float s = g1[i] * rsqrtf(v1[i] + EPSB);
    bias1[i] = b1[i] * s + be1[i] - m1[i] * s;
  } else if (i < 128) {
    int o = i - 64;
    float s = g2[o] * rsqrtf(v2[o] + EPSB);
    bias2[o] = b2[o] * s + be2[o] - m2[o] * s;
  }
}

// ---------------- K12: attention GEMM (32x32) + sigmoid gate + 1x1 conv ----------------
// Gate features read COALESCED from original NCHW f32 feature:
// fixed channel, consecutive lanes -> consecutive pixels (4B stride).
__global__ __launch_bounds__(512, 4) void k12_kernel(
    const float* __restrict__ new_xyz, const float* __restrict__ feature,
    const unsigned short* __restrict__ wAe, const unsigned short* __restrict__ w1e,
    const float* __restrict__ bias1, unsigned short* __restrict__ h1g)
{
  // LDS 38912 B total: B1 [64][168] @0 (21504) | B2 [64][136] @21504 (17408)
  // xyzb [23][72] (3312 B) + lut[160] alias B2.
  __shared__ __align__(16) unsigned char smem[38912];
  unsigned short* B1p  = (unsigned short*)smem;
  unsigned short* B2p  = (unsigned short*)(smem + 21504);
  unsigned short* xyzb = B2p;
  int* lut             = (int*)(smem + 21504 + 3312);

  const int bx = blockIdx.x;
  const int x0 = bx * 64;
  const int y  = blockIdx.y;
  const int n  = blockIdx.z;
  const int tid = threadIdx.x;
  const int lane = tid & 63;
  const int wv = tid >> 6;
  const int r16 = lane & 15;
  const int kq = (lane >> 4) & 3;
  const int l32 = lane & 31;
  const int hi = lane >> 5;
  const int wrow = wv & 3, wcol = wv >> 2;
  const int wh = wrow >> 1;
  const bool xedge = (bx == 0) || (bx == 7);

  // ---- stage new_xyz rows (c,ki) 0..20, width 70 (halo 3) ----
  for (int row = wv; row < 21; row += 8) {
    int c = (row >= 14) ? 2 : (row >= 7 ? 1 : 0);
    int ki = row - c * 7;
    int yy = y + ki - 3;
    bool rowok = (unsigned)yy < 64u;
    unsigned short* dst = xyzb + row * 72;
    if (rowok && !xedge) {
      const float* src = new_xyz + ((n * 3 + c) * 64 + yy) * 512 + (x0 - 3);
      dst[lane] = bfc(src[lane]);
      if (lane < 6) dst[64 + lane] = bfc(src[64 + lane]);
    } else {
      const float* src = new_xyz + ((n * 3 + c) * 64 + yy) * 512;
#pragma unroll
      for (int seg = 0; seg < 2; ++seg) {
        int xx = lane + seg * 64;
        if (xx < 70) {
          int xg = x0 + xx - 3;
          float v = (rowok && (unsigned)xg < 512u) ? src[xg] : 0.f;
          dst[xx] = bfc(v);
        }
      }
    }
  }
  if (tid < 72) { xyzb[21 * 72 + tid] = 0; xyzb[22 * 72 + tid] = 0x3F80; }
  else if (tid >= 128 && tid < 288) {
    int k = tid - 128;
    int off;
    if (k < 147) { int c = k / 49, rem = k - c * 49, ki = rem / 7, kj = rem - ki * 7; off = (c * 7 + ki) * 72 + kj; }
    else if (k == 147) off = 22 * 72;
    else off = 21 * 72;
    lut[k] = off;
  }
  __syncthreads();   // xyzb + lut ready

  // ---- build im2col B1 ----
  {
    int p = tid >> 3, q = tid & 7;
    unsigned short* brow = B1p + p * 168;
#pragma unroll
    for (int j = 0; j < 5; ++j) {
      int k = (q * 5 + j) * 4;
      int o0 = lut[k], o1 = lut[k + 1], o2 = lut[k + 2], o3 = lut[k + 3];
      uint2 w;
      w.x = (unsigned int)xyzb[o0 + p] | ((unsigned int)xyzb[o1 + p] << 16);
      w.y = (unsigned int)xyzb[o2 + p] | ((unsigned int)xyzb[o3 + p] << 16);
      *(uint2*)(brow + k) = w;
    }
  }
  __syncthreads();   // B1 ready; xyzb/lut dead (B2 free)

  const int p32 = 32 * wcol + l32;
  const int ccq = (wrow & 1) * 32;
  const unsigned short* Bp1 = B1p + p32 * 168 + hi * 8;

  // ---- persistent GEMM1 B-fragments (chunk-invariant) ----
  bf16x8 bFr[10];
#pragma unroll
  for (int j = 0; j < 10; ++j) bFr[j] = *(const bf16x8*)(Bp1 + j * 16);

  f32x4 acc2[2];
#pragma unroll
  for (int i = 0; i < 2; ++i) acc2[i] = {0.f, 0.f, 0.f, 0.f};

#pragma unroll
  for (int c = 0; c < 4; ++c) {
    const int kkA = 2 * c + wh;
    const int di = (kkA >= 6) ? 2 : (kkA >= 3 ? 1 : 0);
    const int dj = kkA - 3 * di;

    // ---- prefetch gate features: 16 COALESCED dword loads from NCHW f32 ----
    const int yy = y + di - 1;
    const int xg = x0 + p32 + dj - 1;
    const bool ok = ((unsigned)yy < 64u) && ((unsigned)xg < 512u);
    const float* fbase = feature + (n * 64 * 64 + yy) * 512 + xg;
    float fvv[16];
#pragma unroll
    for (int q = 0; q < 4; ++q) {
      const int c0 = ccq + 8 * q + 4 * hi;
#pragma unroll
      for (int j = 0; j < 4; ++j)
        fvv[4 * q + j] = ok ? fbase[(c0 + j) * 32768] : 0.f;
    }

    // ---- GEMM1 chunk: rows c*128 + wrow*32, K=160 ----
    f32x16 acc1;
#pragma unroll
    for (int i = 0; i < 16; ++i) acc1[i] = 0.f;
    const unsigned short* Ap = wAe + (c * 128 + wrow * 32 + l32) * 160 + hi * 8;
#pragma unroll
    for (int j = 0; j < 10; ++j) {
      bf16x8 a = *(const bf16x8*)(Ap + j * 16);
      acc1 = __builtin_amdgcn_mfma_f32_32x32x16_bf16(a, bFr[j], acc1, 0, 0, 0);
    }

    // ---- gate ----
    unsigned short* brow2 = B2p + p32 * 136 + wrow * 32;
#pragma unroll
    for (int q = 0; q < 4; ++q) {
      int r0 = 8 * q + 4 * hi;
      float s0 = sigm(acc1[4 * q + 0]) * fvv[4 * q + 0];
      float s1 = sigm(acc1[4 * q + 1]) * fvv[4 * q + 1];
      float s2 = sigm(acc1[4 * q + 2]) * fvv[4 * q + 2];
      float s3 = sigm(acc1[4 * q + 3]) * fvv[4 * q + 3];
      uint2 w; w.x = pk2(s0, s1); w.y = pk2(s2, s3);
      *(uint2*)(brow2 + r0) = w;
    }
    __syncthreads();   // B2 chunk written

    // ---- GEMM2 partial, K=128 ----
    const unsigned short* A2p = w1e + (16 * wrow + r16) * 576 + c * 128 + kq * 8;
#pragma unroll
    for (int kst = 0; kst < 4; ++kst) {
      bf16x8 a  = *(const bf16x8*)(A2p + kst * 32);
      bf16x8 b0 = *(const bf16x8*)(B2p + (32 * wcol + r16) * 136 + kst * 32 + kq * 8);
      bf16x8 b1 = *(const bf16x8*)(B2p + (32 * wcol + 16 + r16) * 136 + kst * 32 + kq * 8);
      acc2[0] = __builtin_amdgcn_mfma_f32_16x16x32_bf16(a, b0, acc2[0], 0, 0, 0);
      acc2[1] = __builtin_amdgcn_mfma_f32_16x16x32_bf16(a, b1, acc2[1], 0, 0, 0);
    }
    __syncthreads();   // B2 reads drained before next gate write
  }

  // ---- tail chunk: rows 512..575 (kk=8: di=2, dj=2), GEMM1 by wrow<2 ----
  {
    if (wrow < 2) {
      const int yy = y + 1;
      const int xg = x0 + p32 + 1;
      const bool ok = ((unsigned)yy < 64u) && ((unsigned)xg < 512u);
      const float* fbase = feature + (n * 64 * 64 + yy) * 512 + xg;
      float fvv[16];
#pragma unroll
      for (int q = 0; q < 4; ++q) {
        const int c0 = ccq + 8 * q + 4 * hi;
#pragma unroll
        for (int j = 0; j < 4; ++j)
          fvv[4 * q + j] = ok ? fbase[(c0 + j) * 32768] : 0.f;
      }
      f32x16 acc1;
#pragma unroll
      for (int i = 0; i < 16; ++i) acc1[i] = 0.f;
      const unsigned short* Ap = wAe + (512 + wrow * 32 + l32) * 160 + hi * 8;
#pragma unroll
      for (int j = 0; j < 10; ++j) {
        bf16x8 a = *(const bf16x8*)(Ap + j * 16);
        acc1 = __builtin_amdgcn_mfma_f32_32x32x16_bf16(a, bFr[j], acc1, 0, 0, 0);
      }
      unsigned short* brow2 = B2p + p32 * 136 + wrow * 32;
#pragma unroll
      for (int q = 0; q < 4; ++q) {
        int r0 = 8 * q + 4 * hi;
        float s0 = sigm(acc1[4 * q + 0]) * fvv[4 * q + 0];
        float s1 = sigm(acc1[4 * q + 1]) * fvv[4 * q + 1];
        float s2 = sigm(acc1[4 * q + 2]) * fvv[4 * q + 2];
        float s3 = sigm(acc1[4 * q + 3]) * fvv[4 * q + 3];
        uint2 w; w.x = pk2(s0, s1); w.y = pk2(s2, s3);
        *(uint2*)(brow2 + r0) = w;
      }
    }
    __syncthreads();
    const unsigned short* A2p = w1e + (16 * wrow + r16) * 576 + 512 + kq * 8;
#pragma unroll
    for (int kst = 0; kst < 2; ++kst) {
      bf16x8 a  = *(const bf16x8*)(A2p + kst * 32);
      bf16x8 b0 = *(const bf16x8*)(B2p + (32 * wcol + r16) * 136 + kst * 32 + kq * 8);
      bf16x8 b1 = *(const bf16x8*)(B2p + (32 * wcol + 16 + r16) * 136 + kst * 32 + kq * 8);
      acc2[0] = __builtin_amdgcn_mfma_f32_16x16x32_bf16(a, b0, acc2[0], 0, 0, 0);
      acc2[1] = __builtin_amdgcn_mfma_f32_16x16x32_bf16(a, b1, acc2[1], 0, 0, 0);
    }
    __syncthreads();   // B2 reads drained before epilogue writes
  }

  // ---- epilogue: h1 = relu(acc2 + bias1), transpose via B2 ----
  const int ccb = 16 * wrow + 4 * kq;
  float b1v0 = bias1[ccb], b1v1 = bias1[ccb + 1], b1v2 = bias1[ccb + 2], b1v3 = bias1[ccb + 3];
#pragma unroll
  for (int pf = 0; pf < 2; ++pf) {
    int p = 32 * wcol + 16 * pf + r16;
    uint2 w;
    w.x = pk2(fmaxf(acc2[pf][0] + b1v0, 0.f), fmaxf(acc2[pf][1] + b1v1, 0.f));
    w.y = pk2(fmaxf(acc2[pf][2] + b1v2, 0.f), fmaxf(acc2[pf][3] + b1v3, 0.f));
    *(uint2*)(B2p + p * 136 + ccb) = w;
  }
  __syncthreads();
  {
    int p = tid >> 3, c0 = (tid & 7) * 8;
    uint4 v = *(const uint4*)(B2p + p * 136 + c0);
    *(uint4*)(h1g + (((n * 64 + y) * 512) + x0) * 64 + p * 64 + c0) = v;
  }
}

// ---------------- K3: 3x3 conv 64->64 + BN + ReLU + residual ----------------
__global__ __launch_bounds__(256) void k3_kernel(
    const unsigned short* __restrict__ h1g, const float* __restrict__ feature,
    const unsigned short* __restrict__ w2e, const float* __restrict__ bias2,
    float* __restrict__ out)
{
  __shared__ unsigned short s_h1[3][66][72];

  const int x0 = blockIdx.x * 64;
  const int y  = blockIdx.y;
  const int n  = blockIdx.z;
  const int tid = threadIdx.x;
  const int lane = tid & 63;
  const int wv = tid >> 6;
  const int r16 = lane & 15;
  const int kq = lane >> 4;

  for (int idx = tid; idx < 3 * 66 * 16; idx += 256) {
    int r = idx / (66 * 16), rem = idx - r * 66 * 16, xx = rem >> 4, c0 = (rem & 15) << 2;
    int yy = y + r - 1, xg = x0 + xx - 1;
    uint2 v; v.x = 0u; v.y = 0u;
    if (yy >= 0 && yy < 64 && xg >= 0 && xg < 512)
      v = *(const uint2*)(h1g + (((n * 64 + yy) * 512) + xg) * 64 + c0);
    *(uint2*)(&s_h1[r][xx][c0]) = v;
  }
  __syncthreads();

  f32x4 acc[4];
#pragma unroll
  for (int i = 0; i < 4; ++i) acc[i] = {0.f, 0.f, 0.f, 0.f};

  const unsigned short* Ap = w2e + (16 * wv + r16) * 576 + kq * 8;
#pragma unroll 2
  for (int kst = 0; kst < 18; ++kst) {
    bf16x8 a = *(const bf16x8*)(Ap + kst * 32);
    int kk = kst >> 1, di = kk / 3, dj = kk - di * 3;
    int chalf = (kst & 1) << 5;
#pragma unroll
    for (int pf = 0; pf < 4; ++pf) {
      bf16x8 b = *(const bf16x8*)(&s_h1[di][pf * 16 + r16 + dj][chalf + kq * 8]);
      acc[pf] = __builtin_amdgcn_mfma_f32_16x16x32_bf16(a, b, acc[pf], 0, 0, 0);
    }
  }

#pragma unroll
  for (int pf = 0; pf < 4; ++pf) {
    int p = pf * 16 + r16;
#pragma unroll
    for (int r = 0; r < 4; ++r) {
      int ch = 16 * wv + kq * 4 + r;
      int off = (((n * 64 + ch) * 64) + y) * 512 + x0 + p;
      out[off] = fmaxf(acc[pf][r] + bias2[ch], 0.f) + feature[off];
    }
  }
}

// ---------------- launch ----------------
extern "C" void kernel_launch(void* const* d_in, const int* in_sizes, int n_in,
                              void* d_out, int out_size, void* d_ws, size_t ws_size,
                              hipStream_t stream)
{
  const float* new_xyz = (const float*)d_in[1];
  const float* feature = (const float*)d_in[2];
  const float* w_att = (const float*)d_in[3];
  const float* b_att = (const float*)d_in[4];
  const float* gA  = (const float*)d_in[5];
  const float* beA = (const float*)d_in[6];
  const float* mA  = (const float*)d_in[7];
  const float* vA  = (const float*)d_in[8];
  const float* w1  = (const float*)d_in[9];
  const float* b1  = (const float*)d_in[10];
  const float* g1  = (const float*)d_in[11];
  const float* be1 = (const float*)d_in[12];
  const float* m1  = (const float*)d_in[13];
  const float* v1  = (const float*)d_in[14];
  const float* w2  = (const float*)d_in[15];
  const float* b2  = (const float*)d_in[16];
  const float* g2  = (const float*)d_in[17];
  const float* be2 = (const float*)d_in[18];
  const float* m2  = (const float*)d_in[19];
  const float* v2  = (const float*)d_in[20];

  char* ws = (char*)d_ws;
  unsigned short* wAe = (unsigned short*)(ws);               // 576*160*2 = 184320
  unsigned short* w1e = (unsigned short*)(ws + 184320);      // 64*576*2  =  73728
  unsigned short* w2e = (unsigned short*)(ws + 258048);      // 64*576*2  =  73728
  float* bias1 = (float*)(ws + 331776);                      // 256
  float* bias2 = (float*)(ws + 332032);                      // 256
  unsigned short* h1g = (unsigned short*)(ws + 335872);      // 16 MB

  prep_kernel<<<649, 256, 0, stream>>>(w_att, b_att, gA, beA, mA, vA,
                                       w1, b1, g1, be1, m1, v1,
                                       w2, b2, g2, be2, m2, v2,
                                       wAe, w1e, w2e, bias1, bias2);
  k12_kernel<<<dim3(8, 64, 4), 512, 0, stream>>>(new_xyz, feature, wAe, w1e, bias1, h1g);
  k3_kernel<<<dim3(8, 64, 4), 256, 0, stream>>>(h1g, feature, w2e, bias2, (float*)d_out);
}

// Round 8
// 145.649 us; speedup vs baseline: 1.4762x; 1.0459x over previous
//
#include <hip/hip_runtime.h>

#define EPSB 1e-5f

typedef __bf16 bf16x8 __attribute__((ext_vector_type(8)));
typedef float f32x4 __attribute__((ext_vector_type(4)));
typedef float f32x16 __attribute__((ext_vector_type(16)));

__device__ __forceinline__ unsigned short bfc(float v) {
  __bf16 h = (__bf16)v;
  return __builtin_bit_cast(unsigned short, h);
}
__device__ __forceinline__ unsigned int pk2(float a, float b) {
  return (unsigned int)bfc(a) | ((unsigned int)bfc(b) << 16);
}
__device__ __forceinline__ float sigm(float x) {
  float e = __builtin_amdgcn_exp2f(-x * 1.4426950408889634f);
  return __builtin_amdgcn_rcpf(1.0f + e);
}

// ---------------- prep: fold BN into bf16 weights ----------------
__global__ void prep_kernel(
    const float* __restrict__ w_att, const float* __restrict__ b_att,
    const float* __restrict__ gA, const float* __restrict__ beA,
    const float* __restrict__ mA, const float* __restrict__ vA,
    const float* __restrict__ w1, const float* __restrict__ b1,
    const float* __restrict__ g1, const float* __restrict__ be1,
    const float* __restrict__ m1, const float* __restrict__ v1,
    const float* __restrict__ w2, const float* __restrict__ b2,
    const float* __restrict__ g2, const float* __restrict__ be2,
    const float* __restrict__ m2, const float* __restrict__ v2,
    unsigned short* __restrict__ wAe, unsigned short* __restrict__ w1e,
    unsigned short* __restrict__ w2e, float* __restrict__ bias1,
    float* __restrict__ bias2)
{
  int i = blockIdx.x * 256 + threadIdx.x;
  if (i < 576 * 160) {
    int rp = i / 160, k = i - rp * 160;
    int kk = rp >> 6, cc = rp & 63;
    int o = cc * 9 + kk;
    float s = gA[o] * rsqrtf(vA[o] + EPSB);
    float v = 0.f;
    if (k < 147) {
      int c = k / 49, rem = k - c * 49, ki = rem / 7, kj = rem - ki * 7;
      v = w_att[(o * 3 + c) * 49 + ki * 7 + kj] * s;
    } else if (k == 147) {
      v = b_att[o] * s + beA[o] - mA[o] * s;
    }
    wAe[i] = bfc(v);
    return;
  }
  i -= 576 * 160;
  if (i < 64 * 576) {
    int o = i / 576, kp = i - o * 576;
    int kk = kp >> 6, cc = kp & 63;
    float s = g1[o] * rsqrtf(v1[o] + EPSB);
    w1e[i] = bfc(w1[o * 576 + cc * 9 + kk] * s);
    return;
  }
  i -= 64 * 576;
  if (i < 64 * 576) {
    int o = i / 576, r = i - o * 576, kk = r >> 6, c = r & 63;
    float s = g2[o] * rsqrtf(v2[o] + EPSB);
    w2e[i] = bfc(w2[(o * 64 + c) * 9 + kk] * s);
    return;
  }
  i -= 64 * 576;
  if (i < 64) {
    float s = g1[i] * rsqrtf(v1[i] + EPSB);
    bias1[i] = b1[i] * s + be1[i] - m1[i] * s;
  } else if (i < 128) {
    int o = i - 64;
    float s = g2[o] * rsqrtf(v2[o] + EPSB);
    bias2[o] = b2[o] * s + be2[o] - m2[o] * s;
  }
}

// ---------------- K12: attention GEMM (32x32) + sigmoid gate + 1x1 conv ----------------
// B2 double-buffered -> ONE barrier per chunk. A-frags batch-staged 5-deep.
__global__ __launch_bounds__(512, 4) void k12_kernel(
    const float* __restrict__ new_xyz, const float* __restrict__ feature,
    const unsigned short* __restrict__ wAe, const unsigned short* __restrict__ w1e,
    const float* __restrict__ bias1, unsigned short* __restrict__ h1g)
{
  // LDS 56320 B: B1 [64][168] @0 (21504) | B2 2x[64][136] @21504 (34816)
  // xyzb [23][72] (3312 B) + lut[160] alias B2 buf0.
  __shared__ __align__(16) unsigned char smem[56320];
  unsigned short* B1p  = (unsigned short*)smem;
  unsigned short* B2p  = (unsigned short*)(smem + 21504);
  unsigned short* xyzb = B2p;
  int* lut             = (int*)(smem + 21504 + 3312);

  const int bx = blockIdx.x;
  const int x0 = bx * 64;
  const int y  = blockIdx.y;
  const int n  = blockIdx.z;
  const int tid = threadIdx.x;
  const int lane = tid & 63;
  const int wv = tid >> 6;
  const int r16 = lane & 15;
  const int kq = (lane >> 4) & 3;
  const int l32 = lane & 31;
  const int hi = lane >> 5;
  const int wrow = wv & 3, wcol = wv >> 2;
  const int wh = wrow >> 1;
  const bool xedge = (bx == 0) || (bx == 7);

  // ---- stage new_xyz rows (c,ki) 0..20, width 70 (halo 3) ----
  for (int row = wv; row < 21; row += 8) {
    int c = (row >= 14) ? 2 : (row >= 7 ? 1 : 0);
    int ki = row - c * 7;
    int yy = y + ki - 3;
    bool rowok = (unsigned)yy < 64u;
    unsigned short* dst = xyzb + row * 72;
    if (rowok && !xedge) {
      const float* src = new_xyz + ((n * 3 + c) * 64 + yy) * 512 + (x0 - 3);
      dst[lane] = bfc(src[lane]);
      if (lane < 6) dst[64 + lane] = bfc(src[64 + lane]);
    } else {
      const float* src = new_xyz + ((n * 3 + c) * 64 + yy) * 512;
#pragma unroll
      for (int seg = 0; seg < 2; ++seg) {
        int xx = lane + seg * 64;
        if (xx < 70) {
          int xg = x0 + xx - 3;
          float v = (rowok && (unsigned)xg < 512u) ? src[xg] : 0.f;
          dst[xx] = bfc(v);
        }
      }
    }
  }
  if (tid < 72) { xyzb[21 * 72 + tid] = 0; xyzb[22 * 72 + tid] = 0x3F80; }
  else if (tid >= 128 && tid < 288) {
    int k = tid - 128;
    int off;
    if (k < 147) { int c = k / 49, rem = k - c * 49, ki = rem / 7, kj = rem - ki * 7; off = (c * 7 + ki) * 72 + kj; }
    else if (k == 147) off = 22 * 72;
    else off = 21 * 72;
    lut[k] = off;
  }
  __syncthreads();   // xyzb + lut ready

  // ---- build im2col B1 ----
  {
    int p = tid >> 3, q = tid & 7;
    unsigned short* brow = B1p + p * 168;
#pragma unroll
    for (int j = 0; j < 5; ++j) {
      int k = (q * 5 + j) * 4;
      int o0 = lut[k], o1 = lut[k + 1], o2 = lut[k + 2], o3 = lut[k + 3];
      uint2 w;
      w.x = (unsigned int)xyzb[o0 + p] | ((unsigned int)xyzb[o1 + p] << 16);
      w.y = (unsigned int)xyzb[o2 + p] | ((unsigned int)xyzb[o3 + p] << 16);
      *(uint2*)(brow + k) = w;
    }
  }
  __syncthreads();   // B1 ready; xyzb/lut dead (B2 buffers free)

  const int p32 = 32 * wcol + l32;
  const int ccq = (wrow & 1) * 32;
  const unsigned short* Bp1 = B1p + p32 * 168 + hi * 8;

  f32x4 acc2[2];
#pragma unroll
  for (int i = 0; i < 2; ++i) acc2[i] = {0.f, 0.f, 0.f, 0.f};

#pragma unroll
  for (int c = 0; c < 4; ++c) {
    const int kkA = 2 * c + wh;
    const int di = (kkA >= 6) ? 2 : (kkA >= 3 ? 1 : 0);
    const int dj = kkA - 3 * di;

    // ---- gate feature prefetch: 16 coalesced dword loads (NCHW f32) ----
    const int yy = y + di - 1;
    const int xg = x0 + p32 + dj - 1;
    const bool ok = ((unsigned)yy < 64u) && ((unsigned)xg < 512u);
    const float* fbase = feature + (n * 64 * 64 + yy) * 512 + xg;
    float fvv[16];
#pragma unroll
    for (int q = 0; q < 4; ++q) {
      const int c0 = ccq + 8 * q + 4 * hi;
#pragma unroll
      for (int j = 0; j < 4; ++j)
        fvv[4 * q + j] = ok ? fbase[(c0 + j) * 32768] : 0.f;
    }

    // ---- GEMM1 chunk: rows c*128 + wrow*32, K=160; A staged 5-deep ----
    f32x16 acc1;
#pragma unroll
    for (int i = 0; i < 16; ++i) acc1[i] = 0.f;
    const unsigned short* Ap = wAe + (c * 128 + wrow * 32 + l32) * 160 + hi * 8;
    {
      bf16x8 aF[5];
#pragma unroll
      for (int j = 0; j < 5; ++j) aF[j] = *(const bf16x8*)(Ap + j * 16);
#pragma unroll
      for (int j = 0; j < 5; ++j) {
        bf16x8 b = *(const bf16x8*)(Bp1 + j * 16);
        acc1 = __builtin_amdgcn_mfma_f32_32x32x16_bf16(aF[j], b, acc1, 0, 0, 0);
      }
#pragma unroll
      for (int j = 0; j < 5; ++j) aF[j] = *(const bf16x8*)(Ap + 80 + j * 16);
#pragma unroll
      for (int j = 0; j < 5; ++j) {
        bf16x8 b = *(const bf16x8*)(Bp1 + 80 + j * 16);
        acc1 = __builtin_amdgcn_mfma_f32_32x32x16_bf16(aF[j], b, acc1, 0, 0, 0);
      }
    }

    // ---- GEMM2 A prefetch (overlaps gate + barrier drain) ----
    bf16x8 a2f[4];
    const unsigned short* A2p = w1e + (16 * wrow + r16) * 576 + c * 128 + kq * 8;
#pragma unroll
    for (int kst = 0; kst < 4; ++kst) a2f[kst] = *(const bf16x8*)(A2p + kst * 32);

    // ---- gate -> B2 buffer c&1 ----
    unsigned short* B2b = B2p + (c & 1) * 8704;
    unsigned short* brow2 = B2b + p32 * 136 + wrow * 32;
#pragma unroll
    for (int q = 0; q < 4; ++q) {
      int r0 = 8 * q + 4 * hi;
      float s0 = sigm(acc1[4 * q + 0]) * fvv[4 * q + 0];
      float s1 = sigm(acc1[4 * q + 1]) * fvv[4 * q + 1];
      float s2 = sigm(acc1[4 * q + 2]) * fvv[4 * q + 2];
      float s3 = sigm(acc1[4 * q + 3]) * fvv[4 * q + 3];
      uint2 w; w.x = pk2(s0, s1); w.y = pk2(s2, s3);
      *(uint2*)(brow2 + r0) = w;
    }
    __syncthreads();   // single barrier per chunk (dbuf B2)

    // ---- GEMM2 partial, K=128, reads buf c&1 ----
#pragma unroll
    for (int kst = 0; kst < 4; ++kst) {
      bf16x8 b0 = *(const bf16x8*)(B2b + (32 * wcol + r16) * 136 + kst * 32 + kq * 8);
      bf16x8 b1 = *(const bf16x8*)(B2b + (32 * wcol + 16 + r16) * 136 + kst * 32 + kq * 8);
      acc2[0] = __builtin_amdgcn_mfma_f32_16x16x32_bf16(a2f[kst], b0, acc2[0], 0, 0, 0);
      acc2[1] = __builtin_amdgcn_mfma_f32_16x16x32_bf16(a2f[kst], b1, acc2[1], 0, 0, 0);
    }
  }

  // ---- tail chunk c=4: rows 512..575 (kk=8: di=2, dj=2), GEMM1 by wrow<2, buf0 ----
  {
    if (wrow < 2) {
      const int yy = y + 1;
      const int xg = x0 + p32 + 1;
      const bool ok = ((unsigned)yy < 64u) && ((unsigned)xg < 512u);
      const float* fbase = feature + (n * 64 * 64 + yy) * 512 + xg;
      float fvv[16];
#pragma unroll
      for (int q = 0; q < 4; ++q) {
        const int c0 = ccq + 8 * q + 4 * hi;
#pragma unroll
        for (int j = 0; j < 4; ++j)
          fvv[4 * q + j] = ok ? fbase[(c0 + j) * 32768] : 0.f;
      }
      f32x16 acc1;
#pragma unroll
      for (int i = 0; i < 16; ++i) acc1[i] = 0.f;
      const unsigned short* Ap = wAe + (512 + wrow * 32 + l32) * 160 + hi * 8;
      {
        bf16x8 aF[5];
#pragma unroll
        for (int j = 0; j < 5; ++j) aF[j] = *(const bf16x8*)(Ap + j * 16);
#pragma unroll
        for (int j = 0; j < 5; ++j) {
          bf16x8 b = *(const bf16x8*)(Bp1 + j * 16);
          acc1 = __builtin_amdgcn_mfma_f32_32x32x16_bf16(aF[j], b, acc1, 0, 0, 0);
        }
#pragma unroll
        for (int j = 0; j < 5; ++j) aF[j] = *(const bf16x8*)(Ap + 80 + j * 16);
#pragma unroll
        for (int j = 0; j < 5; ++j) {
          bf16x8 b = *(const bf16x8*)(Bp1 + 80 + j * 16);
          acc1 = __builtin_amdgcn_mfma_f32_32x32x16_bf16(aF[j], b, acc1, 0, 0, 0);
        }
      }
      unsigned short* brow2 = B2p + p32 * 136 + wrow * 32;
#pragma unroll
      for (int q = 0; q < 4; ++q) {
        int r0 = 8 * q + 4 * hi;
        float s0 = sigm(acc1[4 * q + 0]) * fvv[4 * q + 0];
        float s1 = sigm(acc1[4 * q + 1]) * fvv[4 * q + 1];
        float s2 = sigm(acc1[4 * q + 2]) * fvv[4 * q + 2];
        float s3 = sigm(acc1[4 * q + 3]) * fvv[4 * q + 3];
        uint2 w; w.x = pk2(s0, s1); w.y = pk2(s2, s3);
        *(uint2*)(brow2 + r0) = w;
      }
    }
    bf16x8 a2f[2];
    const unsigned short* A2p = w1e + (16 * wrow + r16) * 576 + 512 + kq * 8;
    a2f[0] = *(const bf16x8*)(A2p);
    a2f[1] = *(const bf16x8*)(A2p + 32);
    __syncthreads();
#pragma unroll
    for (int kst = 0; kst < 2; ++kst) {
      bf16x8 b0 = *(const bf16x8*)(B2p + (32 * wcol + r16) * 136 + kst * 32 + kq * 8);
      bf16x8 b1 = *(const bf16x8*)(B2p + (32 * wcol + 16 + r16) * 136 + kst * 32 + kq * 8);
      acc2[0] = __builtin_amdgcn_mfma_f32_16x16x32_bf16(a2f[kst], b0, acc2[0], 0, 0, 0);
      acc2[1] = __builtin_amdgcn_mfma_f32_16x16x32_bf16(a2f[kst], b1, acc2[1], 0, 0, 0);
    }
  }

  // ---- epilogue: h1 = relu(acc2 + bias1), transpose via B2 buf1 (disjoint from buf0 reads) ----
  const int ccb = 16 * wrow + 4 * kq;
  float b1v0 = bias1[ccb], b1v1 = bias1[ccb + 1], b1v2 = bias1[ccb + 2], b1v3 = bias1[ccb + 3];
  unsigned short* sT = B2p + 8704;
#pragma unroll
  for (int pf = 0; pf < 2; ++pf) {
    int p = 32 * wcol + 16 * pf + r16;
    uint2 w;
    w.x = pk2(fmaxf(acc2[pf][0] + b1v0, 0.f), fmaxf(acc2[pf][1] + b1v1, 0.f));
    w.y = pk2(fmaxf(acc2[pf][2] + b1v2, 0.f), fmaxf(acc2[pf][3] + b1v3, 0.f));
    *(uint2*)(sT + p * 136 + ccb) = w;
  }
  __syncthreads();
  {
    int p = tid >> 3, c0 = (tid & 7) * 8;
    uint4 v = *(const uint4*)(sT + p * 136 + c0);
    *(uint4*)(h1g + (((n * 64 + y) * 512) + x0) * 64 + p * 64 + c0) = v;
  }
}

// ---------------- K3: 3x3 conv 64->64 + BN + ReLU + residual ----------------
__global__ __launch_bounds__(256) void k3_kernel(
    const unsigned short* __restrict__ h1g, const float* __restrict__ feature,
    const unsigned short* __restrict__ w2e, const float* __restrict__ bias2,
    float* __restrict__ out)
{
  __shared__ unsigned short s_h1[3][66][72];

  const int x0 = blockIdx.x * 64;
  const int y  = blockIdx.y;
  const int n  = blockIdx.z;
  const int tid = threadIdx.x;
  const int lane = tid & 63;
  const int wv = tid >> 6;
  const int r16 = lane & 15;
  const int kq = lane >> 4;

  for (int idx = tid; idx < 3 * 66 * 16; idx += 256) {
    int r = idx / (66 * 16), rem = idx - r * 66 * 16, xx = rem >> 4, c0 = (rem & 15) << 2;
    int yy = y + r - 1, xg = x0 + xx - 1;
    uint2 v; v.x = 0u; v.y = 0u;
    if (yy >= 0 && yy < 64 && xg >= 0 && xg < 512)
      v = *(const uint2*)(h1g + (((n * 64 + yy) * 512) + xg) * 64 + c0);
    *(uint2*)(&s_h1[r][xx][c0]) = v;
  }
  __syncthreads();

  f32x4 acc[4];
#pragma unroll
  for (int i = 0; i < 4; ++i) acc[i] = {0.f, 0.f, 0.f, 0.f};

  const unsigned short* Ap = w2e + (16 * wv + r16) * 576 + kq * 8;
#pragma unroll 2
  for (int kst = 0; kst < 18; ++kst) {
    bf16x8 a = *(const bf16x8*)(Ap + kst * 32);
    int kk = kst >> 1, di = kk / 3, dj = kk - di * 3;
    int chalf = (kst & 1) << 5;
#pragma unroll
    for (int pf = 0; pf < 4; ++pf) {
      bf16x8 b = *(const bf16x8*)(&s_h1[di][pf * 16 + r16 + dj][chalf + kq * 8]);
      acc[pf] = __builtin_amdgcn_mfma_f32_16x16x32_bf16(a, b, acc[pf], 0, 0, 0);
    }
  }

#pragma unroll
  for (int pf = 0; pf < 4; ++pf) {
    int p = pf * 16 + r16;
#pragma unroll
    for (int r = 0; r < 4; ++r) {
      int ch = 16 * wv + kq * 4 + r;
      int off = (((n * 64 + ch) * 64) + y) * 512 + x0 + p;
      out[off] = fmaxf(acc[pf][r] + bias2[ch], 0.f) + feature[off];
    }
  }
}

// ---------------- launch ----------------
extern "C" void kernel_launch(void* const* d_in, const int* in_sizes, int n_in,
                              void* d_out, int out_size, void* d_ws, size_t ws_size,
                              hipStream_t stream)
{
  const float* new_xyz = (const float*)d_in[1];
  const float* feature = (const float*)d_in[2];
  const float* w_att = (const float*)d_in[3];
  const float* b_att = (const float*)d_in[4];
  const float* gA  = (const float*)d_in[5];
  const float* beA = (const float*)d_in[6];
  const float* mA  = (const float*)d_in[7];
  const float* vA  = (const float*)d_in[8];
  const float* w1  = (const float*)d_in[9];
  const float* b1  = (const float*)d_in[10];
  const float* g1  = (const float*)d_in[11];
  const float* be1 = (const float*)d_in[12];
  const float* m1  = (const float*)d_in[13];
  const float* v1  = (const float*)d_in[14];
  const float* w2  = (const float*)d_in[15];
  const float* b2  = (const float*)d_in[16];
  const float* g2  = (const float*)d_in[17];
  const float* be2 = (const float*)d_in[18];
  const float* m2  = (const float*)d_in[19];
  const float* v2  = (const float*)d_in[20];

  char* ws = (char*)d_ws;
  unsigned short* wAe = (unsigned short*)(ws);               // 576*160*2 = 184320
  unsigned short* w1e = (unsigned short*)(ws + 184320);      // 64*576*2  =  73728
  unsigned short* w2e = (unsigned short*)(ws + 258048);      // 64*576*2  =  73728
  float* bias1 = (float*)(ws + 331776);                      // 256
  float* bias2 = (float*)(ws + 332032);                      // 256
  unsigned short* h1g = (unsigned short*)(ws + 335872);      // 16 MB

  prep_kernel<<<649, 256, 0, stream>>>(w_att, b_att, gA, beA, mA, vA,
                                       w1, b1, g1, be1, m1, v1,
                                       w2, b2, g2, be2, m2, v2,
                                       wAe, w1e, w2e, bias1, bias2);
  k12_kernel<<<dim3(8, 64, 4), 512, 0, stream>>>(new_xyz, feature, wAe, w1e, bias1, h1g);
  k3_kernel<<<dim3(8, 64, 4), 256, 0, stream>>>(h1g, feature, w2e, bias2, (float*)d_out);
}